// Round 10
// baseline (137.498 us; speedup 1.0000x reference)
//
#include <hip/hip_runtime.h>

// MultiScaleSampler R10: zero-LDS MFMA MLP (32x32x16 f16), transposed
// orientation D[out][pt]; layer-to-layer transform = lane<->lane^32 dword
// exchange via v_permlane32_swap_b32 (VALU). vs R9:
//  - swap is builtin-or-INLINE-ASM (never shfl/bpermute -> no LDS pipe)
//  - lanes 0..31 own all 128 pts (4 each): layer-1 B-frags use own registers
//    (h=1 lanes zero) and layer-4 logits land on owner lanes -> 12 fewer
//    swaps, zero cross-lane at input/output edges
//  - __launch_bounds__(256,3) (~168 VGPR) + persistent zero-C f32x16 to let
//    the compiler overlap the 4 independent tile chains (R9's VGPR=64 forced
//    serial chains = exposed latency)

#define W_IMG 2048

typedef __attribute__((ext_vector_type(8)))  _Float16 f16x8;
typedef __attribute__((ext_vector_type(16))) float    f32x16;
typedef __attribute__((ext_vector_type(2)))  __fp16   h16x2;

union DWu { h16x2 h; unsigned u; };
union B8u { f16x8 v; unsigned u[4]; };

// halves-exchange between two registers: x'[32:63]=y[0:31], y'[0:31]=x[32:63]
__device__ __forceinline__ void l32swap(unsigned &x, unsigned &y) {
#if __has_builtin(__builtin_amdgcn_permlane32_swap)
    auto r = __builtin_amdgcn_permlane32_swap(x, y, false, false);
    x = (unsigned)r[0];
    y = (unsigned)r[1];
#else
    asm volatile("v_permlane32_swap_b32 %0, %1" : "+v"(x), "+v"(y));
#endif
}

__device__ __forceinline__ unsigned pkrc(float a, float b) {
    a = fminf(fmaxf(a, 0.f), 60000.f);   // relu + f16-range clamp
    b = fminf(fmaxf(b, 0.f), 60000.f);
    DWu d; d.h = __builtin_amdgcn_cvt_pkrtz(a, b);
    return d.u;
}

__global__ __launch_bounds__(256) void fill_zero(float* __restrict__ out, int n) {
    int n4 = n >> 2;
    float4* o4 = (float4*)out;
    int stride = gridDim.x * blockDim.x;
    for (int i = blockIdx.x * blockDim.x + threadIdx.x; i < n4; i += stride)
        o4[i] = make_float4(0.f, 0.f, 0.f, 0.f);
    int t = (n4 << 2) + (blockIdx.x * blockDim.x + threadIdx.x);
    if (t < n) out[t] = 0.f;
}

__global__ __launch_bounds__(256, 3) void msampler_mlp(
    const float* __restrict__ grid,   // (2, N)
    const int*   __restrict__ yi,     // (N,)
    const float* __restrict__ m,      // (3,3)
    const float* __restrict__ W1, const float* __restrict__ b1,   // (5,32),(32)
    const float* __restrict__ W2, const float* __restrict__ b2,   // (32,32),(32)
    const float* __restrict__ W3, const float* __restrict__ b3,   // (32,32),(32)
    const float* __restrict__ W4, const float* __restrict__ b4,   // (32,3),(3)
    float* __restrict__ out, int N)
{
    const int tid  = threadIdx.x;
    const int lane = tid & 63;
    const int wave = tid >> 6;
    const int m32  = lane & 31;   // row (A) / col (B,D)
    const int h    = lane >> 5;   // k-half selector

    // ---- A fragments (A = W^T: A[m=out][k=in]); k = q*16 + 8h + j ----
    B8u a1;                       // layer 1, K=16: k<5 weights, k=5 bias
#pragma unroll
    for (int j = 0; j < 8; ++j) {
        int k = 8*h + j;
        float w = 0.f;
        if (h == 0) {
            if (k < 5)       w = W1[k*32 + m32];
            else if (k == 5) w = b1[m32];
        }
        a1.v[j] = (_Float16)w;
    }
    B8u a2[2], a3[2], a4[2];
#pragma unroll
    for (int q = 0; q < 2; ++q) {
#pragma unroll
        for (int j = 0; j < 8; ++j) {
            int k = q*16 + 8*h + j;
            a2[q].v[j] = (_Float16)W2[k*32 + m32];
            a3[q].v[j] = (_Float16)W3[k*32 + m32];
            a4[q].v[j] = (m32 < 3) ? (_Float16)W4[k*3 + m32] : (_Float16)0.f;
        }
    }
    // bias C-inits for layers 2,3 (row = (r&3) + 8*(r>>2) + 4h)
    f32x16 cb2, cb3, zacc;
#pragma unroll
    for (int r = 0; r < 16; ++r) {
        int row = (r & 3) + 8*(r >> 2) + 4*h;
        cb2[r] = b2[row];
        cb3[r] = b3[row];
        zacc[r] = 0.f;
    }
    const float B40 = b4[0], B41 = b4[1], B42 = b4[2];

    // ---- uniform homography scalars ----
    float m20 = m[6], m21 = m[7], m22 = m[8];
    float det = m[0]*(m[4]*m22 - m[5]*m21)
              - m[1]*(m[3]*m22 - m[5]*m20)
              + m[2]*(m[3]*m21 - m[4]*m20);
    float adet = fabsf(det);

    // ---- features: lanes 0..31 own 4 pts each (pt = i0 + t*32 + m32) ----
    const int i0 = blockIdx.x * 512 + wave * 128;
    int ya[4];
    unsigned fdw[4][3];
    if (lane < 32) {
#pragma unroll
        for (int t = 0; t < 4; ++t) {
            int i  = i0 + t*32 + m32;
            int ic = i < N ? i : N - 1;
            float gx = grid[ic];
            float gy = grid[N + ic];
            int   y  = yi[ic];
            ya[t] = y;
            int py = y >> 11;            // / 2048
            int px = y & (W_IMG - 1);    // % 2048
            float denom = m20*(float)px + m21*(float)py + m22;
            float ad    = fabsf(denom);
            float dsda  = fminf(adet / (ad*ad*ad), 60000.f);
            float fx = gx - floorf(gx);
            float fy = gy - floorf(gy);
            DWu d0; d0.h = __builtin_amdgcn_cvt_pkrtz(fx, fy);
            DWu d1; d1.h = __builtin_amdgcn_cvt_pkrtz(1.f - fx, 1.f - fy);
            DWu d2; d2.h = __builtin_amdgcn_cvt_pkrtz(dsda, 1.f);  // 1.0 = bias
            fdw[t][0] = d0.u; fdw[t][1] = d1.u; fdw[t][2] = d2.u;
        }
    }

    float lg[4][3];   // logits (valid on lanes 0..31)

#define PACKSWAP(ACC, BA, BB)                                                 \
    {                                                                         \
        unsigned dw0 = pkrc(ACC[0],  ACC[1]);                                 \
        unsigned dw1 = pkrc(ACC[2],  ACC[3]);                                 \
        unsigned dw2 = pkrc(ACC[4],  ACC[5]);                                 \
        unsigned dw3 = pkrc(ACC[6],  ACC[7]);                                 \
        unsigned dw4 = pkrc(ACC[8],  ACC[9]);                                 \
        unsigned dw5 = pkrc(ACC[10], ACC[11]);                                \
        unsigned dw6 = pkrc(ACC[12], ACC[13]);                                \
        unsigned dw7 = pkrc(ACC[14], ACC[15]);                                \
        l32swap(dw0, dw2); l32swap(dw1, dw3);                                 \
        l32swap(dw4, dw6); l32swap(dw5, dw7);                                 \
        BA.u[0]=dw0; BA.u[1]=dw1; BA.u[2]=dw2; BA.u[3]=dw3;                   \
        BB.u[0]=dw4; BB.u[1]=dw5; BB.u[2]=dw6; BB.u[3]=dw7;                   \
    }

#pragma unroll
    for (int t = 0; t < 4; ++t) {
        // layer-1 B frag: h=0 lanes hold own features, h=1 lanes zero
        B8u bf;
        bf.u[0] = (h == 0) ? fdw[t][0] : 0u;
        bf.u[1] = (h == 0) ? fdw[t][1] : 0u;
        bf.u[2] = (h == 0) ? fdw[t][2] : 0u;
        bf.u[3] = 0u;

        // layer 1 (bias via k=5 slot, C=0)
        f32x16 acc = __builtin_amdgcn_mfma_f32_32x32x16_f16(a1.v, bf.v, zacc, 0, 0, 0);

        B8u bA, bB;
        PACKSWAP(acc, bA, bB)

        // layer 2 (C = bias)
        acc = __builtin_amdgcn_mfma_f32_32x32x16_f16(a2[0].v, bA.v, cb2, 0, 0, 0);
        acc = __builtin_amdgcn_mfma_f32_32x32x16_f16(a2[1].v, bB.v, acc, 0, 0, 0);
        PACKSWAP(acc, bA, bB)

        // layer 3
        acc = __builtin_amdgcn_mfma_f32_32x32x16_f16(a3[0].v, bA.v, cb3, 0, 0, 0);
        acc = __builtin_amdgcn_mfma_f32_32x32x16_f16(a3[1].v, bB.v, acc, 0, 0, 0);
        PACKSWAP(acc, bA, bB)

        // layer 4 (C=0); logits = regs 0..2 on h=0 lanes = pt owner lanes
        f32x16 acc4 = __builtin_amdgcn_mfma_f32_32x32x16_f16(a4[0].v, bA.v, zacc, 0, 0, 0);
        acc4 = __builtin_amdgcn_mfma_f32_32x32x16_f16(a4[1].v, bB.v, acc4, 0, 0, 0);
        lg[t][0] = acc4[0]; lg[t][1] = acc4[1]; lg[t][2] = acc4[2];
    }
#undef PACKSWAP

    // ---- softmax + scatter (lanes 0..31, 4 pts each) ----
    if (lane < 32) {
#pragma unroll
        for (int t = 0; t < 4; ++t) {
            float l0 = lg[t][0] + B40;
            float l1 = lg[t][1] + B41;
            float l2 = lg[t][2] + B42;
            float mx = fmaxf(l0, fmaxf(l1, l2));
            float e0 = __expf(l0 - mx), e1 = __expf(l1 - mx), e2 = __expf(l2 - mx);
            float inv = 1.f / (e0 + e1 + e2);
            int i = i0 + t*32 + m32;
            if (i < N) {
                int o = ya[t] * 3;
                out[o + 0] = e0 * inv;
                out[o + 1] = e1 * inv;
                out[o + 2] = e2 * inv;
            }
        }
    }
}

extern "C" void kernel_launch(void* const* d_in, const int* in_sizes, int n_in,
                              void* d_out, int out_size, void* d_ws, size_t ws_size,
                              hipStream_t stream) {
    const float* grid = (const float*)d_in[0];
    const int*   yi   = (const int*)  d_in[1];
    const float* m    = (const float*)d_in[2];
    const float* W1   = (const float*)d_in[3];
    const float* b1   = (const float*)d_in[4];
    const float* W2   = (const float*)d_in[5];
    const float* b2   = (const float*)d_in[6];
    const float* W3   = (const float*)d_in[7];
    const float* b3   = (const float*)d_in[8];
    const float* W4   = (const float*)d_in[9];
    const float* b4   = (const float*)d_in[10];
    float* out = (float*)d_out;

    int N = in_sizes[1];  // yi element count

    fill_zero<<<2048, 256, 0, stream>>>(out, out_size);

    int grid_sz = (N + 511) / 512;   // 512 pts/block (4 waves x 128)
    msampler_mlp<<<grid_sz, 256, 0, stream>>>(
        grid, yi, m, W1, b1, W2, b2, W3, b3, W4, b4, out, N);
}